// Round 1
// baseline (78.907 us; speedup 1.0000x reference)
//
#include <hip/hip_runtime.h>

#define DIM 4096
#define NB 128
// padded float2 strides inside LDS state buffer: addr = i0*S0 + i1*S1 + i2
#define S1 17
#define S0 274

__global__ __launch_bounds__(256)
void ulayer_kernel(const float* __restrict__ thetas,
                   const float* __restrict__ evecs,
                   const float* __restrict__ evals,
                   const float* __restrict__ sre,
                   const float* __restrict__ sim,
                   float* __restrict__ out)
{
    __shared__ float  sV[256];
    __shared__ float  sC[48];
    __shared__ float  sS[48];
    __shared__ float2 sG[3][16][16];
    __shared__ float2 st[16 * S0];   // 4384 float2 = 35072 B

    const int t = threadIdx.x;
    const int b = blockIdx.x;

    // stage V and per-(gate,eig) trig
    sV[t] = evecs[t];
    if (t < 48) {
        const int g = t >> 4, k = t & 15;
        const float a = thetas[g] * evals[k];
        float sn, cs;
        sincosf(a, &sn, &cs);
        sC[t] = cs;
        sS[t] = sn;
    }

    // issue global state loads early (consumed after the barrier)
    const float4* __restrict__ vre = (const float4*)(sre + (size_t)b * DIM);
    const float4* __restrict__ vim = (const float4*)(sim + (size_t)b * DIM);
    float4 lre[4], lim[4];
#pragma unroll
    for (int it = 0; it < 4; ++it) {
        lre[it] = vre[t + 256 * it];
        lim[it] = vim[t + 256 * it];
    }

    __syncthreads();

    // build the three 16x16 complex gates: U[i,j] = sum_k V[i,k]V[j,k] * (cos - i sin)
#pragma unroll
    for (int rep = 0; rep < 3; ++rep) {
        const int e = t + (rep << 8);
        const int g = e >> 8;
        const int i = (e >> 4) & 15;
        const int j = e & 15;
        float gr = 0.f, gi = 0.f;
#pragma unroll
        for (int k = 0; k < 16; ++k) {
            const float vv = sV[i * 16 + k] * sV[j * 16 + k];
            gr = fmaf(vv,  sC[(g << 4) + k], gr);
            gi = fmaf(vv, -sS[(g << 4) + k], gi);
        }
        sG[g][i][j] = make_float2(gr, gi);
    }

    // scatter state into padded interleaved LDS layout
#pragma unroll
    for (int it = 0; it < 4; ++it) {
        const int e0 = (t + 256 * it) << 2;      // element index, multiple of 4
        const int i0 = e0 >> 8;
        const int r  = e0 & 255;                 // i1*16 + i2
        const int base = i0 * S0 + (r >> 4) * S1 + (r & 15);
        const float* pr = (const float*)&lre[it];
        const float* pi = (const float*)&lim[it];
#pragma unroll
        for (int q = 0; q < 4; ++q)
            st[base + q] = make_float2(pr[q], pi[q]);
    }
    __syncthreads();

    const int h = t >> 4;
    const int k = t & 15;

    // in-place fiber-per-thread contraction along one axis
    auto pass = [&](const int gidx, const int base, const int stride) {
        float2 x[16];
#pragma unroll
        for (int j = 0; j < 16; ++j) x[j] = st[base + j * stride];
        float2 y[16];
#pragma unroll
        for (int i = 0; i < 16; ++i) {
            float ar = 0.f, ai = 0.f;
#pragma unroll
            for (int j = 0; j < 16; ++j) {
                const float2 g = sG[gidx][i][j];
                ar = fmaf(g.x,  x[j].x, ar);
                ar = fmaf(-g.y, x[j].y, ar);
                ai = fmaf(g.x,  x[j].y, ai);
                ai = fmaf(g.y,  x[j].x, ai);
            }
            y[i] = make_float2(ar, ai);
        }
#pragma unroll
        for (int i = 0; i < 16; ++i) st[base + i * stride] = y[i];
    };

    // axis2 (innermost, gate U2): fiber (i0=h, i1=k), stride 1
    pass(2, h * S0 + k * S1, 1);
    __syncthreads();
    // axis1 (gate U1): fiber (i0=h, i2=k), stride S1
    pass(1, h * S0 + k, S1);
    __syncthreads();
    // axis0 (gate U0): fiber (i1=h, i2=k), stride S0
    pass(0, h * S1 + k, S0);
    __syncthreads();

    // write out [2][NB][DIM]
    float* __restrict__ ore = out + (size_t)b * DIM;
    float* __restrict__ oim = out + (size_t)NB * DIM + (size_t)b * DIM;
#pragma unroll
    for (int it = 0; it < 4; ++it) {
        const int e0 = (t + 256 * it) << 2;
        const int i0 = e0 >> 8;
        const int r  = e0 & 255;
        const int base = i0 * S0 + (r >> 4) * S1 + (r & 15);
        float4 xr, xi;
        float* qr = (float*)&xr;
        float* qi = (float*)&xi;
#pragma unroll
        for (int q = 0; q < 4; ++q) {
            const float2 v = st[base + q];
            qr[q] = v.x;
            qi[q] = v.y;
        }
        *(float4*)(ore + e0) = xr;
        *(float4*)(oim + e0) = xi;
    }
}

extern "C" void kernel_launch(void* const* d_in, const int* in_sizes, int n_in,
                              void* d_out, int out_size, void* d_ws, size_t ws_size,
                              hipStream_t stream) {
    const float* thetas = (const float*)d_in[0];
    const float* evecs  = (const float*)d_in[1];
    const float* evals  = (const float*)d_in[2];
    const float* sre    = (const float*)d_in[3];
    const float* sim    = (const float*)d_in[4];
    float* out = (float*)d_out;
    ulayer_kernel<<<NB, 256, 0, stream>>>(thetas, evecs, evals, sre, sim, out);
}

// Round 2
// 70.163 us; speedup vs baseline: 1.1246x; 1.1246x over previous
//
#include <hip/hip_runtime.h>

#define DIM 4096
#define NB 128
#define NT 512
// padded float2 strides inside LDS state buffer: addr = i0*S0 + i1*S1 + i2
#define S1 17
#define S0 274

__global__ __launch_bounds__(NT)
void ulayer_kernel(const float* __restrict__ thetas,
                   const float* __restrict__ evecs,
                   const float* __restrict__ evals,
                   const float* __restrict__ sre,
                   const float* __restrict__ sim,
                   float* __restrict__ out)
{
    __shared__ float  sV[256];
    __shared__ float  sC[48];
    __shared__ float  sS[48];
    __shared__ float2 sG[3][16][16];
    __shared__ float2 st[16 * S0];   // 4384 float2 = 35072 B

    const int t = threadIdx.x;
    const int b = blockIdx.x;

    // stage V (threads 0..255) and per-(gate,eig) trig (threads 256..303) in parallel
    if (t < 256) sV[t] = evecs[t];
    else if (t < 304) {
        const int e = t - 256;
        const int g = e >> 4, k = e & 15;
        float sn, cs;
        sincosf(thetas[g] * evals[k], &sn, &cs);
        sC[e] = cs;
        sS[e] = sn;
    }

    // issue global state loads early (consumed at scatter time)
    const float4* __restrict__ vre = (const float4*)(sre + (size_t)b * DIM);
    const float4* __restrict__ vim = (const float4*)(sim + (size_t)b * DIM);
    float4 lre[2], lim[2];
#pragma unroll
    for (int it = 0; it < 2; ++it) {
        lre[it] = vre[t + NT * it];
        lim[it] = vim[t + NT * it];
    }

    __syncthreads();

    // build the three 16x16 complex gates: U[i,j] = sum_k V[i,k]V[j,k] * (cos - i sin)
#pragma unroll
    for (int rep = 0; rep < 2; ++rep) {
        const int e = t + (rep << 9);
        if (e < 768) {
            const int g = e >> 8;
            const int i = (e >> 4) & 15;
            const int j = e & 15;
            float gr = 0.f, gi = 0.f;
#pragma unroll
            for (int k = 0; k < 16; ++k) {
                const float vv = sV[i * 16 + k] * sV[j * 16 + k];
                gr = fmaf(vv,  sC[(g << 4) + k], gr);
                gi = fmaf(vv, -sS[(g << 4) + k], gi);
            }
            sG[g][i][j] = make_float2(gr, gi);
        }
    }

    // scatter state into padded interleaved LDS layout
#pragma unroll
    for (int it = 0; it < 2; ++it) {
        const int e0 = (t + NT * it) << 2;       // element index, multiple of 4
        const int i0 = e0 >> 8;
        const int r  = e0 & 255;                 // i1*16 + i2
        const int base = i0 * S0 + (r >> 4) * S1 + (r & 15);
        const float* pr = (const float*)&lre[it];
        const float* pi = (const float*)&lim[it];
#pragma unroll
        for (int q = 0; q < 4; ++q)
            st[base + q] = make_float2(pr[q], pi[q]);
    }
    __syncthreads();

    // thread decomposition: fg = fiber group (64), ih = row-pair (8)
    const int fg = t & 63;
    const int ih = t >> 6;
    const int r0 = ih * 2;       // this thread's two gate rows: r0, r0+1

    // One contraction pass. Each thread: 4 fibers (f = fg + 64*fl), rows {r0,r0+1}.
    // Gate rows live in registers (wave-uniform LDS broadcast, loaded once).
    // All x reads happen before the barrier; writes after => in-place safe.
    auto pass = [&](const int gidx, const int BH, const int BK, const int STRIDE) {
        float2 g0[16], g1[16];
#pragma unroll
        for (int j = 0; j < 16; ++j) {
            g0[j] = sG[gidx][r0][j];
            g1[j] = sG[gidx][r0 + 1][j];
        }
        float2 y0[4], y1[4];
#pragma unroll
        for (int fl = 0; fl < 4; ++fl) {
            const int f = fg + 64 * fl;
            const int h = f >> 4;
            const int k = f & 15;
            const int base = h * BH + k * BK;
            float2 x[16];
#pragma unroll
            for (int j = 0; j < 16; ++j) x[j] = st[base + j * STRIDE];
            float ar0 = 0.f, ai0 = 0.f, ar1 = 0.f, ai1 = 0.f;
#pragma unroll
            for (int j = 0; j < 16; ++j) {
                ar0 = fmaf(g0[j].x,  x[j].x, ar0);
                ar0 = fmaf(-g0[j].y, x[j].y, ar0);
                ai0 = fmaf(g0[j].x,  x[j].y, ai0);
                ai0 = fmaf(g0[j].y,  x[j].x, ai0);
                ar1 = fmaf(g1[j].x,  x[j].x, ar1);
                ar1 = fmaf(-g1[j].y, x[j].y, ar1);
                ai1 = fmaf(g1[j].x,  x[j].y, ai1);
                ai1 = fmaf(g1[j].y,  x[j].x, ai1);
            }
            y0[fl] = make_float2(ar0, ai0);
            y1[fl] = make_float2(ar1, ai1);
        }
        __syncthreads();
#pragma unroll
        for (int fl = 0; fl < 4; ++fl) {
            const int f = fg + 64 * fl;
            const int h = f >> 4;
            const int k = f & 15;
            const int base = h * BH + k * BK;
            st[base + r0 * STRIDE]       = y0[fl];
            st[base + (r0 + 1) * STRIDE] = y1[fl];
        }
        __syncthreads();
    };

    // axis2 (innermost, gate U2): fiber (i0=h, i1=k), stride 1
    pass(2, S0, S1, 1);
    // axis1 (gate U1): fiber (i0=h, i2=k), stride S1
    pass(1, S0, 1, S1);
    // axis0 (gate U0): fiber (i1=h, i2=k), stride S0
    pass(0, S1, 1, S0);

    // write out [2][NB][DIM]
    float* __restrict__ ore = out + (size_t)b * DIM;
    float* __restrict__ oim = out + (size_t)NB * DIM + (size_t)b * DIM;
#pragma unroll
    for (int it = 0; it < 2; ++it) {
        const int e0 = (t + NT * it) << 2;
        const int i0 = e0 >> 8;
        const int r  = e0 & 255;
        const int base = i0 * S0 + (r >> 4) * S1 + (r & 15);
        float4 xr, xi;
        float* qr = (float*)&xr;
        float* qi = (float*)&xi;
#pragma unroll
        for (int q = 0; q < 4; ++q) {
            const float2 v = st[base + q];
            qr[q] = v.x;
            qi[q] = v.y;
        }
        *(float4*)(ore + e0) = xr;
        *(float4*)(oim + e0) = xi;
    }
}

extern "C" void kernel_launch(void* const* d_in, const int* in_sizes, int n_in,
                              void* d_out, int out_size, void* d_ws, size_t ws_size,
                              hipStream_t stream) {
    const float* thetas = (const float*)d_in[0];
    const float* evecs  = (const float*)d_in[1];
    const float* evals  = (const float*)d_in[2];
    const float* sre    = (const float*)d_in[3];
    const float* sim    = (const float*)d_in[4];
    float* out = (float*)d_out;
    ulayer_kernel<<<NB, NT, 0, stream>>>(thetas, evecs, evals, sre, sim, out);
}